// Round 11
// baseline (236.586 us; speedup 1.0000x reference)
//
#include <hip/hip_runtime.h>

// Top2Gating, S=8192, E=64, capacity=256. Output f32 flat:
//   [ l_aux (1) | combine (S*E*CAP) | dispatch (S*E*CAP) ] = 1 + 2*SEC words.
// Window design: output = 16384 windows of 16384 words at w*TBLK (64KB-aligned).
// Window w word 0 ("straddle") = previous token-block's last element (l_aux for w=0).
// Kernel order (stream-ordered, no cross-block races):
//   gate -> scan -> emit(records+straddles) -> stream(zero words 256..16K, PURE fill)
//   -> patch(words 1..255 + scattered nonzeros >=256, from intact records).
// Compact scratch in windows 16377..16382 words [8..): consumed by end of emit;
// leftovers cleaned by patch (words 8..255) and stream (words 256+).

namespace {
constexpr int  TOK  = 8192;
constexpr int  NEXP = 64;
constexpr int  CAPC = 256;
constexpr int  CHK  = 64;                           // one wave per chunk rank-phase
constexpr int  NCHK = TOK / CHK;                    // 128
constexpr long long TBLK = (long long)NEXP * CAPC;  // 16384 words per window
constexpr long long SEC  = (long long)TOK * TBLK;   // words per dense section
constexpr float NEGMIN = -3.402823466e38f;          // finfo(f32).min
constexpr float EPSF   = 1.1920929e-7f;             // finfo(f32).eps
constexpr long long PK_OFF  = 16377LL * TBLK + 8;   // pk  = i1|i2<<8|r1<<16|r2<<24
constexpr long long G1_OFF  = 16378LL * TBLK + 8;   // gate1 value
constexpr long long G2_OFF  = 16379LL * TBLK + 8;   // gate2 value
constexpr long long H12_OFF = 16380LL * TBLK + 8;   // h1 | h2<<16 per (chunk,expert)
constexpr long long ME_OFF  = 16381LL * TBLK + 8;   // me partial per (chunk,expert)
constexpr long long B12_OFF = 16382LL * TBLK + 8;   // b1 | b2full<<16 per (chunk,expert)
// per-window record (words w*TBLK + 0..4), written by emit, read by patch:
//   [0] straddle FINAL value (untouched after emit/scan)
//   [1] rec0=i1|i2<<8|k1<<16|k2<<17  [2] rec1=loc1|loc2<<16  [3] v1  [4] v2
}

typedef float f32x4 __attribute__((ext_vector_type(4)));

__device__ __forceinline__ float wave_max64(float v) {
    for (int o = 32; o; o >>= 1) v = fmaxf(v, __shfl_xor(v, o));
    return v;
}
__device__ __forceinline__ float wave_sum64(float v) {
    for (int o = 32; o; o >>= 1) v += __shfl_xor(v, o);
    return v;
}

// ---- Phase 1: gating + one-wave ballot-match ranks. 128 blocks x 512 threads.
__global__ __launch_bounds__(512) void tg_gate(const float* __restrict__ logits,
                                               const float* __restrict__ noise,
                                               float* __restrict__ out)
{
    __shared__ int   i12s[CHK];
    __shared__ float g1s[CHK], g2s[CHK];
    __shared__ int   lr1s[CHK], lr2s[CHK];
    __shared__ int   cnt[2][NEXP];
    __shared__ float meSh[512];
    const int tid = threadIdx.x, lane = tid & 63, wv = tid >> 6;   // 8 waves
    const int c = blockIdx.x;

    if (tid < 128) cnt[tid >> 6][tid & 63] = 0;

    float meAcc = 0.f;
    #pragma unroll
    for (int i = 0; i < CHK / 8; ++i) {             // 8 rows per wave
        const int rloc = i * 8 + wv;
        const int row  = c * CHK + rloc;
        const float l = logits[row * NEXP + lane];
        const float n = noise [row * NEXP + lane];

        const float m    = wave_max64(l);
        const float ex   = __expf(l - m);
        const float sm   = wave_sum64(ex);
        const float gate = ex / sm;

        const unsigned long long b1 = __ballot(l == m);     // argmax(gates)==argmax(logits)
        const int   i1 = __ffsll(b1) - 1;                   // first max wins
        const float G1 = __shfl(gate, i1);

        const float lw = (lane == i1) ? NEGMIN : (l + n);   // mask winner with finfo.min
        const float m2 = wave_max64(lw);
        const unsigned long long b2 = __ballot(lw == m2);
        const int   i2 = __ffsll(b2) - 1;
        const float G2 = __shfl(gate, i2);

        if (lane == 0) {
            i12s[rloc] = i1 | (i2 << 8);
            g1s[rloc]  = G1;
            g2s[rloc]  = G2;
        }
        meAcc += gate;
    }
    meSh[tid] = meAcc;
    __syncthreads();

    // match phase: wave 0 = first choice, wave 1 = second; chunk == one wave.
    if (wv < 2) {
        const int sel = wv;
        const int pk  = i12s[lane];
        const int e   = sel ? ((pk >> 8) & 255) : (pk & 255);
        unsigned long long m = ~0ull;
        #pragma unroll
        for (int b = 0; b < 6; ++b) {
            const unsigned long long bb = __ballot((e >> b) & 1);
            m &= ((e >> b) & 1) ? bb : ~bb;         // lanes choosing same expert
        }
        const unsigned long long below = (1ull << lane) - 1;
        (sel ? lr2s : lr1s)[lane] = __popcll(m & below);    // rank among earlier tokens
        if ((m & below) == 0) cnt[sel][e] = __popcll(m);    // leader records group size
    }
    __syncthreads();

    int* outi = (int*)out;
    if (tid < CHK) {
        const int pk = i12s[tid];
        outi[PK_OFF + c * CHK + tid] = (pk & 0xffff) | (lr1s[tid] << 16) | (lr2s[tid] << 24);
        out [G1_OFF + c * CHK + tid] = g1s[tid];
        out [G2_OFF + c * CHK + tid] = g2s[tid];
    }
    if (tid < NEXP) {
        outi[H12_OFF + c * NEXP + tid] = cnt[0][tid] | (cnt[1][tid] << 16);
        float s = 0.f;
        #pragma unroll
        for (int w = 0; w < 8; ++w) s += meSh[w * 64 + tid];
        out[ME_OFF + c * NEXP + tid] = s;
    }
}

// ---- Phase 2: cross-chunk scan (two coalesced passes, registers only) + l_aux.
__global__ __launch_bounds__(64) void tg_scan(float* __restrict__ out)
{
    const int e = threadIdx.x;                      // one lane per expert
    const int* outi = (const int*)out;
    int* wbi = (int*)out;

    int t1 = 0, t2 = 0;
    float ms = 0.f;
    for (int c = 0; c < NCHK; ++c) {                // pass 1: totals
        const int h = outi[H12_OFF + c * NEXP + e];
        t1 += h & 0xffff;
        t2 += h >> 16;
        ms += out[ME_OFF + c * NEXP + e];
    }
    int p1 = 0, p2 = t1;                            // b2full = excl prefix2 + tot1
    for (int c = 0; c < NCHK; ++c) {                // pass 2: exclusive prefixes
        const int h = outi[H12_OFF + c * NEXP + e];
        wbi[B12_OFF + c * NEXP + e] = p1 | (p2 << 16);
        p1 += h & 0xffff;
        p2 += h >> 16;
    }
    float term = (ms * (1.f / TOK)) * ((float)t1 * (1.f / TOK)) * (float)(NEXP * NEXP);
    term = wave_sum64(term);
    if (e == 0) out[0] = term * (1.f / NEXP);       // l_aux (window 0 straddle)
}

// ---- Phase 3: per-token finalize -> records (words 1..4) + straddles (word 0 of
//      next window; s=8191 dispatch case lands exactly on the buffer's last word).
__global__ __launch_bounds__(256) void tg_emit(float* __restrict__ out)
{
    const int s = blockIdx.x * 256 + threadIdx.x;   // one thread per token
    const int c = s >> 6;                           // CHK=64
    const int* outi = (const int*)out;
    const int   pk = outi[PK_OFF + s];
    const float G1 = out[G1_OFF + s];
    const float G2 = out[G2_OFF + s];
    const int i1 = pk & 255, i2 = (pk >> 8) & 255;
    const unsigned b1w = (unsigned)outi[B12_OFF + c * NEXP + i1];
    const unsigned b2w = (unsigned)outi[B12_OFF + c * NEXP + i2];
    const int loc1 = (int)(b1w & 0xffffu) + ((pk >> 16) & 255);
    const int loc2 = (int)(b2w >> 16)     + ((pk >> 24) & 255);

    const bool k1 = loc1 < CAPC, k2 = loc2 < CAPC;
    const float ge1 = k1 ? G1 : 0.f, ge2 = k2 ? G2 : 0.f;
    const float dn  = fmaxf(ge1 + ge2, EPSF);       // post-drop renormalization
    const float w1 = ge1 / dn, w2 = ge2 / dn;
    const int rec0 = i1 | (i2 << 8) | (k1 ? 1 << 16 : 0) | (k2 ? 1 << 17 : 0);
    const int rec1 = (k1 ? loc1 : 0) | ((k2 ? loc2 : 0) << 16);
    const int j1 = k1 ? (i1 * CAPC + loc1 + 1) : -1;   // window-local word, 1..16384
    const int j2 = k2 ? (i2 * CAPC + loc2 + 1) : -1;

    long long h = (long long)s * TBLK;              // combine window
    ((int*)out)[h + 1] = rec0;
    ((int*)out)[h + 2] = rec1;
    out[h + 3] = w1;
    out[h + 4] = w2;
    out[h + TBLK] = (j1 == (int)TBLK) ? w1 : ((j2 == (int)TBLK) ? w2 : 0.f);

    h = (long long)(TOK + s) * TBLK;                // dispatch window
    ((int*)out)[h + 1] = rec0;
    ((int*)out)[h + 2] = rec1;
    out[h + 3] = 1.f;
    out[h + 4] = 1.f;
    out[h + TBLK] = (j1 == (int)TBLK || j2 == (int)TBLK) ? 1.f : 0.f;
}

// ---- Phase 4: PURE zero stream of words [256, 16384) of every window.
//      No loads, no VALU chain, no waits, plain f32x4 stores == fill clone.
__global__ __launch_bounds__(256) void tg_stream(float* __restrict__ out)
{
    const int lane = threadIdx.x & 63, wv = threadIdx.x >> 6;
    const int w = blockIdx.x * 4 + wv;              // 0..16383
    f32x4* b4 = (f32x4*)(out + (long long)w * TBLK);
    const f32x4 z = {0.f, 0.f, 0.f, 0.f};
    #pragma unroll
    for (int i = 1; i < 64; ++i)                    // skip words 0..255
        b4[i * 64 + lane] = z;
}

// ---- Phase 5: patch. One wave per window: read intact record, write words 1..255
//      (zeros + in-range nonzeros), scatter nonzeros with j in [256, 16384).
__global__ __launch_bounds__(256) void tg_patch(float* __restrict__ out)
{
    const int lane = threadIdx.x & 63, wv = threadIdx.x >> 6;
    const int w = blockIdx.x * 4 + wv;              // 0..16383
    float* base = out + (long long)w * TBLK;

    const f32x4 A  = *(const f32x4*)base;           // words 0..3 (record intact)
    const float v2 = base[4];
    const int  rec0 = __float_as_int(A.y);
    const int  rec1 = __float_as_int(A.z);
    const float v1  = A.w;
    const bool k1 = (rec0 >> 16) & 1, k2 = (rec0 >> 17) & 1;
    const int  i1 = rec0 & 255, i2 = (rec0 >> 8) & 255;
    const int  j1 = k1 ? (i1 * CAPC + (rec1 & 0xffff) + 1) : -1;
    const int  j2 = k2 ? (i2 * CAPC + (rec1 >> 16) + 1) : -1;

    #pragma unroll
    for (int u = 0; u < 4; ++u) {                   // words 1..255 (skip straddle @0)
        const int q = lane * 4 + u;
        if (q == 0) continue;
        base[q] = (q == j1) ? v1 : ((q == j2) ? v2 : 0.f);
    }
    if (lane == 0) {                                // nonzeros in the streamed region
        if (k1 && j1 >= 256 && j1 < (int)TBLK) base[j1] = v1;
        if (k2 && j2 >= 256 && j2 < (int)TBLK) base[j2] = v2;
    }
}

extern "C" void kernel_launch(void* const* d_in, const int* in_sizes, int n_in,
                              void* d_out, int out_size, void* d_ws, size_t ws_size,
                              hipStream_t stream)
{
    (void)d_ws; (void)ws_size; (void)in_sizes; (void)n_in; (void)out_size;
    const float* logits = (const float*)d_in[0];
    const float* noise  = (const float*)d_in[1];
    float* out = (float*)d_out;

    tg_gate  <<<NCHK,      512, 0, stream>>>(logits, noise, out);
    tg_scan  <<<1,          64, 0, stream>>>(out);
    tg_emit  <<<TOK / 256, 256, 0, stream>>>(out);
    tg_stream<<<4096,      256, 0, stream>>>(out);  // 16384 windows, 1/wave
    tg_patch <<<4096,      256, 0, stream>>>(out);
}

// Round 12
// 210.200 us; speedup vs baseline: 1.1255x; 1.1255x over previous
//
#include <hip/hip_runtime.h>

// Top2Gating, S=8192, E=64, capacity=256. Output f32 flat:
//   [ l_aux (1) | combine (S*E*CAP) | dispatch (S*E*CAP) ] = 1 + 2*SEC words.
// Window design: output = 16384 windows of 16384 words at w*TBLK (64KB-aligned).
// Window w word 0 ("straddle") = previous token-block's last element (l_aux for w=0).
// gate -> scan(parallel) -> emit(records+straddles) -> write(zero-stream+patch).
// Compact scratch in windows 16377..16382 words [8..): consumed by emit; zeroed by write.

namespace {
constexpr int  TOK  = 8192;
constexpr int  NEXP = 64;
constexpr int  CAPC = 256;
constexpr int  CHK  = 64;                           // one wave per chunk rank-phase
constexpr int  NCHK = TOK / CHK;                    // 128
constexpr long long TBLK = (long long)NEXP * CAPC;  // 16384 words per window
constexpr long long SEC  = (long long)TOK * TBLK;   // words per dense section
constexpr float NEGMIN = -3.402823466e38f;          // finfo(f32).min
constexpr float EPSF   = 1.1920929e-7f;             // finfo(f32).eps
constexpr long long PK_OFF  = 16377LL * TBLK + 8;   // pk  = i1|i2<<8|r1<<16|r2<<24
constexpr long long G1_OFF  = 16378LL * TBLK + 8;   // gate1 value
constexpr long long G2_OFF  = 16379LL * TBLK + 8;   // gate2 value
constexpr long long H12_OFF = 16380LL * TBLK + 8;   // h1 | h2<<16 per (chunk,expert)
constexpr long long ME_OFF  = 16381LL * TBLK + 8;   // me partial per (chunk,expert)
constexpr long long B12_OFF = 16382LL * TBLK + 8;   // b1 | b2full<<16 per (chunk,expert)
// per-window record (words w*TBLK + 0..4), written by emit, read by write:
//   [0] straddle FINAL value  [1] rec0=i1|i2<<8|k1<<16|k2<<17
//   [2] rec1=loc1|loc2<<16    [3] v1  [4] v2
}

typedef float f32x4 __attribute__((ext_vector_type(4)));

__device__ __forceinline__ float wave_max64(float v) {
    for (int o = 32; o; o >>= 1) v = fmaxf(v, __shfl_xor(v, o));
    return v;
}
__device__ __forceinline__ float wave_sum64(float v) {
    for (int o = 32; o; o >>= 1) v += __shfl_xor(v, o);
    return v;
}

// ---- Phase 1: gating + one-wave ballot-match ranks. 128 blocks x 512 threads.
__global__ __launch_bounds__(512) void tg_gate(const float* __restrict__ logits,
                                               const float* __restrict__ noise,
                                               float* __restrict__ out)
{
    __shared__ int   i12s[CHK];
    __shared__ float g1s[CHK], g2s[CHK];
    __shared__ int   lr1s[CHK], lr2s[CHK];
    __shared__ int   cnt[2][NEXP];
    __shared__ float meSh[512];
    const int tid = threadIdx.x, lane = tid & 63, wv = tid >> 6;   // 8 waves
    const int c = blockIdx.x;

    if (tid < 128) cnt[tid >> 6][tid & 63] = 0;

    float meAcc = 0.f;
    #pragma unroll
    for (int i = 0; i < CHK / 8; ++i) {             // 8 rows per wave
        const int rloc = i * 8 + wv;
        const int row  = c * CHK + rloc;
        const float l = logits[row * NEXP + lane];
        const float n = noise [row * NEXP + lane];

        const float m    = wave_max64(l);
        const float ex   = __expf(l - m);
        const float sm   = wave_sum64(ex);
        const float gate = ex / sm;

        const unsigned long long b1 = __ballot(l == m);     // argmax(gates)==argmax(logits)
        const int   i1 = __ffsll(b1) - 1;                   // first max wins
        const float G1 = __shfl(gate, i1);

        const float lw = (lane == i1) ? NEGMIN : (l + n);   // mask winner with finfo.min
        const float m2 = wave_max64(lw);
        const unsigned long long b2 = __ballot(lw == m2);
        const int   i2 = __ffsll(b2) - 1;
        const float G2 = __shfl(gate, i2);

        if (lane == 0) {
            i12s[rloc] = i1 | (i2 << 8);
            g1s[rloc]  = G1;
            g2s[rloc]  = G2;
        }
        meAcc += gate;
    }
    meSh[tid] = meAcc;
    __syncthreads();

    // match phase: wave 0 = first choice, wave 1 = second; chunk == one wave.
    if (wv < 2) {
        const int sel = wv;
        const int pk  = i12s[lane];
        const int e   = sel ? ((pk >> 8) & 255) : (pk & 255);
        unsigned long long m = ~0ull;
        #pragma unroll
        for (int b = 0; b < 6; ++b) {
            const unsigned long long bb = __ballot((e >> b) & 1);
            m &= ((e >> b) & 1) ? bb : ~bb;         // lanes choosing same expert
        }
        const unsigned long long below = (1ull << lane) - 1;
        (sel ? lr2s : lr1s)[lane] = __popcll(m & below);    // rank among earlier tokens
        if ((m & below) == 0) cnt[sel][e] = __popcll(m);    // leader records group size
    }
    __syncthreads();

    int* outi = (int*)out;
    if (tid < CHK) {
        const int pk = i12s[tid];
        outi[PK_OFF + c * CHK + tid] = (pk & 0xffff) | (lr1s[tid] << 16) | (lr2s[tid] << 24);
        out [G1_OFF + c * CHK + tid] = g1s[tid];
        out [G2_OFF + c * CHK + tid] = g2s[tid];
    }
    if (tid < NEXP) {
        outi[H12_OFF + c * NEXP + tid] = cnt[0][tid] | (cnt[1][tid] << 16);
        float s = 0.f;
        #pragma unroll
        for (int w = 0; w < 8; ++w) s += meSh[w * 64 + tid];
        out[ME_OFF + c * NEXP + tid] = s;
    }
}

// ---- Phase 2: PARALLEL cross-chunk scan. 256 threads = 4 quarters x 64 experts;
//      each thread handles 32 chunks with unrolled independent loads (ILP),
//      quarter offsets combined via LDS. Serial depth ~34 instead of 256.
__global__ __launch_bounds__(256) void tg_scan(float* __restrict__ out)
{
    __shared__ int   s1[4][NEXP], s2[4][NEXP];
    __shared__ float sm[4][NEXP];
    const int tid = threadIdx.x, e = tid & 63, q = tid >> 6;
    const int* outi = (const int*)out;

    int t1 = 0, t2 = 0;
    float ms = 0.f;
    #pragma unroll
    for (int i = 0; i < NCHK / 4; ++i) {            // quarter totals (32 indep loads)
        const int c = q * (NCHK / 4) + i;
        const int h = outi[H12_OFF + c * NEXP + e];
        t1 += h & 0xffff;
        t2 += h >> 16;
        ms += out[ME_OFF + c * NEXP + e];
    }
    s1[q][e] = t1; s2[q][e] = t2; sm[q][e] = ms;
    __syncthreads();

    int off1 = 0, off2 = 0, T1 = 0;
    float MS = 0.f;
    #pragma unroll
    for (int qq = 0; qq < 4; ++qq) {                // exclusive quarter offsets + totals
        if (qq < q) { off1 += s1[qq][e]; off2 += s2[qq][e]; }
        T1 += s1[qq][e];
        MS += sm[qq][e];
    }

    int p1 = off1, p2 = T1 + off2;                  // b2full = excl prefix2 + tot1
    int* wbi = (int*)out;
    #pragma unroll
    for (int i = 0; i < NCHK / 4; ++i) {            // write bases (re-reads are L2-hot)
        const int c = q * (NCHK / 4) + i;
        const int h = outi[H12_OFF + c * NEXP + e];
        wbi[B12_OFF + c * NEXP + e] = p1 | (p2 << 16);
        p1 += h & 0xffff;
        p2 += h >> 16;
    }

    if (q == 0) {                                   // l_aux (window 0 straddle)
        float term = (MS * (1.f / TOK)) * ((float)T1 * (1.f / TOK)) * (float)(NEXP * NEXP);
        term = wave_sum64(term);
        if (e == 0) out[0] = term * (1.f / NEXP);
    }
}

// ---- Phase 3: per-token finalize -> records (words 1..4) + straddles (word 0 of
//      next window; s=8191 dispatch case lands exactly on the buffer's last word).
__global__ __launch_bounds__(256) void tg_emit(float* __restrict__ out)
{
    const int s = blockIdx.x * 256 + threadIdx.x;   // one thread per token
    const int c = s >> 6;                           // CHK=64
    const int* outi = (const int*)out;
    const int   pk = outi[PK_OFF + s];
    const float G1 = out[G1_OFF + s];
    const float G2 = out[G2_OFF + s];
    const int i1 = pk & 255, i2 = (pk >> 8) & 255;
    const unsigned b1w = (unsigned)outi[B12_OFF + c * NEXP + i1];
    const unsigned b2w = (unsigned)outi[B12_OFF + c * NEXP + i2];
    const int loc1 = (int)(b1w & 0xffffu) + ((pk >> 16) & 255);
    const int loc2 = (int)(b2w >> 16)     + ((pk >> 24) & 255);

    const bool k1 = loc1 < CAPC, k2 = loc2 < CAPC;
    const float ge1 = k1 ? G1 : 0.f, ge2 = k2 ? G2 : 0.f;
    const float dn  = fmaxf(ge1 + ge2, EPSF);       // post-drop renormalization
    const float w1 = ge1 / dn, w2 = ge2 / dn;
    const int rec0 = i1 | (i2 << 8) | (k1 ? 1 << 16 : 0) | (k2 ? 1 << 17 : 0);
    const int rec1 = (k1 ? loc1 : 0) | ((k2 ? loc2 : 0) << 16);
    const int j1 = k1 ? (i1 * CAPC + loc1 + 1) : -1;   // window-local word, 1..16384
    const int j2 = k2 ? (i2 * CAPC + loc2 + 1) : -1;

    long long h = (long long)s * TBLK;              // combine window
    ((int*)out)[h + 1] = rec0;
    ((int*)out)[h + 2] = rec1;
    out[h + 3] = w1;
    out[h + 4] = w2;
    out[h + TBLK] = (j1 == (int)TBLK) ? w1 : ((j2 == (int)TBLK) ? w2 : 0.f);

    h = (long long)(TOK + s) * TBLK;                // dispatch window
    ((int*)out)[h + 1] = rec0;
    ((int*)out)[h + 2] = rec1;
    out[h + 3] = 1.f;
    out[h + 4] = 1.f;
    out[h + TBLK] = (j1 == (int)TBLK || j2 == (int)TBLK) ? 1.f : 0.f;
}

// ---- Phase 4: dense writer, one WAVE per window, zero-stream + patch.
//      Loop body is a pure NT store of a constant zero vector (no VALU chain);
//      after vmcnt(0), lane 0 patches straddle + <=2 nonzeros.
__global__ __launch_bounds__(256) void tg_write(float* __restrict__ out)
{
    const int lane = threadIdx.x & 63, wv = threadIdx.x >> 6;
    const int w = blockIdx.x * 4 + wv;              // 0..16383
    float* base = out + (long long)w * TBLK;        // 64KB-aligned

    // record load (wave-lockstep; compiler orders aliasing stores after it)
    const f32x4 A  = *(const f32x4*)base;
    const float v2 = base[4];
    const float sv  = A.x;
    const int  rec0 = __float_as_int(A.y);
    const int  rec1 = __float_as_int(A.z);
    const float v1  = A.w;
    const bool k1 = (rec0 >> 16) & 1, k2 = (rec0 >> 17) & 1;
    const int  i1 = rec0 & 255, i2 = (rec0 >> 8) & 255;
    const int  j1 = i1 * CAPC + (rec1 & 0xffff) + 1;
    const int  j2 = i2 * CAPC + (rec1 >> 16) + 1;

    f32x4* b4 = (f32x4*)base;
    const f32x4 z = {0.f, 0.f, 0.f, 0.f};
    #pragma unroll
    for (int i = 0; i < 64; ++i)
        __builtin_nontemporal_store(z, &b4[i * 64 + lane]);

    // drain stores, then patch (same-wave same-address ordering via vmcnt(0))
    asm volatile("s_waitcnt vmcnt(0)" ::: "memory");
    if (lane == 0) {
        base[0] = sv;                               // straddle / l_aux
        if (k1) base[j1] = v1;
        if (k2) base[j2] = v2;
    }
}

extern "C" void kernel_launch(void* const* d_in, const int* in_sizes, int n_in,
                              void* d_out, int out_size, void* d_ws, size_t ws_size,
                              hipStream_t stream)
{
    (void)d_ws; (void)ws_size; (void)in_sizes; (void)n_in; (void)out_size;
    const float* logits = (const float*)d_in[0];
    const float* noise  = (const float*)d_in[1];
    float* out = (float*)d_out;

    tg_gate <<<NCHK,      512, 0, stream>>>(logits, noise, out);
    tg_scan <<<1,         256, 0, stream>>>(out);
    tg_emit <<<TOK / 256, 256, 0, stream>>>(out);
    tg_write<<<TOK / 2,   256, 0, stream>>>(out);   // 4096 blocks, 4 windows each
}